// Round 9
// baseline (505.682 us; speedup 1.0000x reference)
//
#include <hip/hip_runtime.h>
#include <hip/hip_bf16.h>

#define N_NODES 100000
#define N_EDGES 1200000
#define N_GRAPH 1000
#define F_INN   7
#define HDIM    64
#define GFEAT   10
#define T_OUT   5
#define EPSF    1e-5f
#define NBLK_SCAN ((N_NODES + 255) / 256)   // 391
#define NG64    ((N_NODES + 63) / 64)       // 1563
#define NBUK    ((N_NODES + 255) / 256)     // 391 buckets of 256 nodes
#define EPB     4096                        // edges per block (count/scatter)
#define NBLK_E  ((N_EDGES + EPB - 1) / EPB) // 293

// flags: [0]=edge wide(int64) [1]=batch wide [2]=1D fp32 [3]=world fp32

__device__ __forceinline__ float ldf(const void* p, int i, int isf32) {
    return isf32 ? ((const float*)p)[i]
                 : __bfloat162float(((const __hip_bfloat16*)p)[i]);
}
__device__ __forceinline__ float u_lo(unsigned u) { return __uint_as_float(u << 16); }
__device__ __forceinline__ float u_hi(unsigned u) { return __uint_as_float(u & 0xFFFF0000u); }
// spill-proof: named float4 accumulators only
__device__ __forceinline__ void upadd4(uint4 u, float4& p, float4& q) {
    p.x += u_lo(u.x); p.y += u_hi(u.x);
    p.z += u_lo(u.y); p.w += u_hi(u.y);
    q.x += u_lo(u.z); q.y += u_hi(u.z);
    q.z += u_lo(u.w); q.w += u_hi(u.w);
}
__device__ __forceinline__ int ld_src(const int* edge, int e, int wide) {
    return wide ? edge[2 * e] : edge[e];
}
__device__ __forceinline__ int ld_dst(const int* edge, int e, int wide) {
    return wide ? edge[2 * (N_EDGES + e)] : edge[N_EDGES + e];
}
__device__ __forceinline__ int ld_batch(const int* batch, int v, int wide) {
    return wide ? batch[2 * v] : batch[v];
}

__global__ void SimpleGCN_6640019440134_kernel() {}

__global__ void s22_fill(float* out, int n, float val) {
    int i = blockIdx.x * blockDim.x + threadIdx.x;
    if (i < n) out[i] = val;
}

__global__ void __launch_bounds__(256) s22_probe(const int* edge, const int* batch,
                                                 const unsigned* g1,
                                                 const unsigned short* x,
                                                 const unsigned short* W1,
                                                 const unsigned short* W2,
                                                 int* flags) {
    __shared__ int sh[8];
    int t = threadIdx.x;
    if (t < 8) sh[t] = 0;
    __syncthreads();
    { int pos = 1 + 2 * 4687 * t; if (edge[pos] != 0) atomicOr(&sh[0], 1); }
    { int pos = (N_NODES - 511) + 2 * t; if (batch[pos] != 0) atomicOr(&sh[1], 1); }
    if (t < 16 && g1[t] != 0x3F800000u) atomicOr(&sh[2], 1);
    {
        int e = (x[t] >> 7) & 0xFF;  if (e >= 100 && e <= 140) atomicAdd(&sh[3], 1);
        e = (W1[t] >> 7) & 0xFF;     if (e >= 100 && e <= 140) atomicAdd(&sh[4], 1);
        e = (W2[t] >> 7) & 0xFF;     if (e >= 100 && e <= 140) atomicAdd(&sh[5], 1);
    }
    __syncthreads();
    if (t == 0) {
        flags[0] = (sh[0] == 0);
        flags[1] = (sh[1] == 0);
        flags[2] = (sh[2] == 0);
        int fx = (sh[3] < 192), fw1 = (sh[4] < 192), fw2 = (sh[5] < 192);
        flags[3] = (fx + fw1 + fw2 >= 2);
    }
}

__global__ void s22_zero(int* zbuf, int zcount) {
    int i = blockIdx.x * blockDim.x + threadIdx.x;
    if (i < zcount) zbuf[i] = 0;
}

// ---- bucketed CSR build: count -> scan buckets -> scatter packed -> fine fill ----
// bucket b covers dst nodes [b*256, b*256+256); packed word = src | (dst&255)<<17

__global__ void __launch_bounds__(256) s23_count(const int* __restrict__ edge,
                                                 int* __restrict__ bin_total,
                                                 const int* __restrict__ fl) {
    __shared__ int hist[NBUK];
    int wide = fl[0];
    int t = threadIdx.x;
    for (int i = t; i < NBUK; i += 256) hist[i] = 0;
    __syncthreads();
    int e0 = blockIdx.x * EPB;
    int e1 = min(e0 + EPB, N_EDGES);
    for (int e = e0 + t; e < e1; e += 256) {
        unsigned d = (unsigned)ld_dst(edge, e, wide);
        unsigned s = (unsigned)ld_src(edge, e, wide);
        if (s < N_NODES && d < N_NODES) atomicAdd(&hist[d >> 8], 1);
    }
    __syncthreads();
    for (int i = t; i < NBUK; i += 256) {
        int c = hist[i];
        if (c) atomicAdd(&bin_total[i * 16], c);   // line-padded counters
    }
}

__global__ void __launch_bounds__(512) s23_scanbk(const int* __restrict__ bin_total,
                                                  int* __restrict__ bbase,
                                                  int* __restrict__ bin_cursor) {
    __shared__ int tmp[512];
    int t = threadIdx.x;
    int v = (t < NBUK) ? bin_total[t * 16] : 0;
    tmp[t] = v;
    __syncthreads();
    for (int o = 1; o < 512; o <<= 1) {
        int a = (t >= o) ? tmp[t - o] : 0;
        __syncthreads();
        tmp[t] += a;
        __syncthreads();
    }
    if (t < NBUK) {
        int b = tmp[t] - v;       // exclusive prefix = bucket base
        bbase[t] = b;
        bin_cursor[t * 16] = b;
    }
}

__global__ void __launch_bounds__(256) s23_scatter(const int* __restrict__ edge,
                                                   int* __restrict__ bin_cursor,
                                                   int* __restrict__ packed,
                                                   const int* __restrict__ fl) {
    __shared__ int hist[NBUK];
    __shared__ int bloc[NBUK];
    int wide = fl[0];
    int t = threadIdx.x;
    for (int i = t; i < NBUK; i += 256) hist[i] = 0;
    __syncthreads();
    int e0 = blockIdx.x * EPB;
    int e1 = min(e0 + EPB, N_EDGES);
    for (int e = e0 + t; e < e1; e += 256) {
        unsigned d = (unsigned)ld_dst(edge, e, wide);
        unsigned s = (unsigned)ld_src(edge, e, wide);
        if (s < N_NODES && d < N_NODES) atomicAdd(&hist[d >> 8], 1);
    }
    __syncthreads();
    for (int i = t; i < NBUK; i += 256) {
        int c = hist[i];
        bloc[i] = c ? atomicAdd(&bin_cursor[i * 16], c) : 0;  // one alloc per (block,bucket)
        hist[i] = 0;                                          // reuse as rank counter
    }
    __syncthreads();
    for (int e = e0 + t; e < e1; e += 256) {
        unsigned d = (unsigned)ld_dst(edge, e, wide);
        unsigned s = (unsigned)ld_src(edge, e, wide);
        if (s < N_NODES && d < N_NODES) {
            int b = (int)(d >> 8);
            int r = atomicAdd(&hist[b], 1);
            packed[bloc[b] + r] = (int)s | ((int)(d & 255u) << 17);
        }
    }
}

// rank-scatter (no sort — wave-per-node gathers can't exploit it) + fused x̃ prep
__global__ void __launch_bounds__(256) s23_fill(const int* __restrict__ packed,
                                                const int* __restrict__ bbase,
                                                const int* __restrict__ bin_total,
                                                int* __restrict__ csr_src,
                                                int* __restrict__ cursor,
                                                float* __restrict__ dis,
                                                const void* x,
                                                __hip_bfloat16* __restrict__ xt,
                                                const int* __restrict__ fl) {
    __shared__ int ldeg[256];
    __shared__ int lrank[256];
    __shared__ int lstart[256];
    __shared__ int tmp[256];
    int b = blockIdx.x, t = threadIdx.x;
    int pb = bbase[b];
    int cnt = bin_total[b * 16];
    int fw = fl[3];
    ldeg[t] = 0; lrank[t] = 0;
    __syncthreads();
    for (int i = t; i < cnt; i += 256) {
        int vl = packed[pb + i] >> 17;
        atomicAdd(&ldeg[vl], 1);
    }
    __syncthreads();
    int dv = ldeg[t];
    tmp[t] = dv;
    __syncthreads();
    for (int o = 1; o < 256; o <<= 1) {
        int a = (t >= o) ? tmp[t - o] : 0;
        __syncthreads();
        tmp[t] += a;
        __syncthreads();
    }
    lstart[t] = tmp[t] - dv;           // bucket-local exclusive prefix
    int v = b * 256 + t;
    if (v < N_NODES) {
        cursor[v] = pb + tmp[t];       // global inclusive end offset
        float dvf = rsqrtf((float)dv + 1.0f);
        dis[v] = dvf;
#pragma unroll
        for (int c = 0; c < 8; c++) {
            float val = (c < F_INN) ? ldf(x, v * F_INN + c, fw) * dvf : 0.f;
            xt[(size_t)v * 8 + c] = __float2bfloat16(val);
        }
    }
    __syncthreads();
    for (int i = t; i < cnt; i += 256) {
        int p = packed[pb + i];
        int vl = p >> 17;
        int r = atomicAdd(&lrank[vl], 1);
        csr_src[pb + lstart[vl] + r] = p & 0x1FFFF;
    }
}

// ---- layer-1 gather (16 B rows, table 1.6 MB = always L2-hot) + fused BN1 moments ----

__global__ void __launch_bounds__(256) s28_gather_x_mom(const __hip_bfloat16* __restrict__ xt,
                                                        const float* __restrict__ dis,
                                                        const int* __restrict__ cursor,
                                                        const int* __restrict__ csr,
                                                        float* __restrict__ aggx,
                                                        float* __restrict__ mom) {
    const uint4* rows = (const uint4*)xt;
    int t = threadIdx.x, lane = t & 63, sub = t >> 6;
    float m[7] = {0, 0, 0, 0, 0, 0, 0};
    float M[28];
#pragma unroll
    for (int i = 0; i < 28; i++) M[i] = 0.f;
    for (int grp = blockIdx.x * 4 + sub; grp < NG64; grp += gridDim.x * 4) {
        int v = grp * 64 + lane;
        if (v >= N_NODES) continue;
        int end = cursor[v];
        int start = (v == 0) ? 0 : cursor[v - 1];
        float4 b0 = make_float4(0.f, 0.f, 0.f, 0.f);
        float4 b1 = make_float4(0.f, 0.f, 0.f, 0.f);
        { uint4 u = rows[v]; upadd4(u, b0, b1); }
        int j = start;
        for (; j + 3 < end; j += 4) {
            uint4 u0 = rows[csr[j]], u1 = rows[csr[j + 1]];
            uint4 u2 = rows[csr[j + 2]], u3 = rows[csr[j + 3]];
            upadd4(u0, b0, b1); upadd4(u1, b0, b1);
            upadd4(u2, b0, b1); upadd4(u3, b0, b1);
        }
        for (; j < end; j++) { uint4 u = rows[csr[j]]; upadd4(u, b0, b1); }
        float dv = dis[v];
        float av[7] = {b0.x * dv, b0.y * dv, b0.z * dv, b0.w * dv,
                       b1.x * dv, b1.y * dv, b1.z * dv};
        float4* dst = (float4*)&aggx[(size_t)v * 8];
        dst[0] = make_float4(av[0], av[1], av[2], av[3]);
        dst[1] = make_float4(av[4], av[5], av[6], b1.w * dv);
#pragma unroll
        for (int c = 0; c < 7; c++) m[c] += av[c];
        int idx = 0;
#pragma unroll
        for (int c = 0; c < 7; c++)
#pragma unroll
            for (int d = c; d < 7; d++) { M[idx] += av[c] * av[d]; idx++; }
    }
#pragma unroll
    for (int c = 0; c < 7; c++)
        for (int mm = 1; mm < 64; mm <<= 1) m[c] += __shfl_xor(m[c], mm);
#pragma unroll
    for (int i = 0; i < 28; i++)
        for (int mm = 1; mm < 64; mm <<= 1) M[i] += __shfl_xor(M[i], mm);
    __shared__ float ws[4][35];
    if (lane == 0) {
#pragma unroll
        for (int c = 0; c < 7; c++) ws[sub][c] = m[c];
#pragma unroll
        for (int i = 0; i < 28; i++) ws[sub][7 + i] = M[i];
    }
    __syncthreads();
    if (t < 35) {
        float tot = ws[0][t] + ws[1][t] + ws[2][t] + ws[3][t];
        atomicAdd(&mom[t], tot);
    }
}

__global__ void s24_bn1(const float* __restrict__ mom, const void* W1, const void* b1,
                        const void* gamma, const void* beta,
                        float* scale, float* shift, const int* __restrict__ fl) {
    int fw = fl[3], f1d = fl[2];
    int j = threadIdx.x;   // 64 threads
    float w[7];
#pragma unroll
    for (int c = 0; c < 7; c++) w[c] = ldf(W1, c * HDIM + j, fw);
    float b = ldf(b1, j, f1d);
    const float invN = 1.0f / (float)N_NODES;
    float meanP = 0.f;
#pragma unroll
    for (int c = 0; c < 7; c++) meanP += mom[c] * w[c];
    meanP *= invN;
    float E2 = 0.f;
    int idx = 0;
#pragma unroll
    for (int c = 0; c < 7; c++)
#pragma unroll
        for (int d = c; d < 7; d++) {
            float f = (c == d) ? 1.f : 2.f;
            E2 += f * mom[7 + idx] * w[c] * w[d];
            idx++;
        }
    E2 *= invN;
    float mean = meanP + b;
    float var = E2 + 2.f * b * meanP + b * b - mean * mean;
    float sc = ldf(gamma, j, f1d) * rsqrtf(var + EPSF);
    scale[j] = sc;
    shift[j] = ldf(beta, j, f1d) + (b - mean) * sc;   // includes bias fold
}

// ---- layer-2 prep: agg(8f) -> h=agg@W1 -> bn/relu/dis -> @W2 -> yt (bf16) ----
// yt layout: single [N][64] bf16 (128 B rows)

__global__ void __launch_bounds__(256) s24_prep2(const float* __restrict__ aggx,
                                                 const void* W1, const void* W2,
                                                 const float* __restrict__ scale,
                                                 const float* __restrict__ shift,
                                                 const float* __restrict__ dis,
                                                 __hip_bfloat16* __restrict__ yt,
                                                 const int* __restrict__ fl) {
    int fw = fl[3];
    __shared__ float rows[4][HDIM];
    int t = threadIdx.x, lane = t & 63, sub = t >> 6;
    float w1r[7], wr[64];
    if (fw) {
        const float* Wa = (const float*)W1;
        const float* Wb = (const float*)W2;
#pragma unroll
        for (int c = 0; c < 7; c++) w1r[c] = Wa[c * HDIM + lane];
#pragma unroll
        for (int k = 0; k < 64; k++) wr[k] = Wb[k * HDIM + lane];
    } else {
        const __hip_bfloat16* Wa = (const __hip_bfloat16*)W1;
        const __hip_bfloat16* Wb = (const __hip_bfloat16*)W2;
#pragma unroll
        for (int c = 0; c < 7; c++) w1r[c] = __bfloat162float(Wa[c * HDIM + lane]);
#pragma unroll
        for (int k = 0; k < 64; k++) wr[k] = __bfloat162float(Wb[k * HDIM + lane]);
    }
    float sc = scale[lane], sh = shift[lane];
    for (int v = blockIdx.x * 4 + sub; v < N_NODES; v += gridDim.x * 4) {
        const float4* p = (const float4*)&aggx[(size_t)v * 8];
        float4 a0 = p[0], a1 = p[1];
        float hb = a0.x * w1r[0] + a0.y * w1r[1] + a0.z * w1r[2] + a0.w * w1r[3]
                 + a1.x * w1r[4] + a1.y * w1r[5] + a1.z * w1r[6];
        float r = fmaxf(hb * sc + sh, 0.f) * dis[v];
        rows[sub][lane] = r;      // wave-private row; lockstep => no barrier
        float acc = 0.f;
#pragma unroll
        for (int k4 = 0; k4 < 16; k4++) {
            float4 rr = *(const float4*)&rows[sub][k4 * 4];
            acc += rr.x * wr[k4 * 4 + 0] + rr.y * wr[k4 * 4 + 1]
                 + rr.z * wr[k4 * 4 + 2] + rr.w * wr[k4 * 4 + 3];
        }
        yt[(size_t)v * HDIM + lane] = __float2bfloat16(acc);
    }
}

// ---- layer-3 prep: bufB(h2) -> bn/relu/dis -> @W3 -> yt (bf16) ----

__global__ void __launch_bounds__(256) s24_prep3(const float* __restrict__ bufB,
                                                 const void* W3,
                                                 const float* __restrict__ scale,
                                                 const float* __restrict__ shift,
                                                 const float* __restrict__ dis,
                                                 __hip_bfloat16* __restrict__ yt,
                                                 const int* __restrict__ fl) {
    int fw = fl[3];
    __shared__ float rows[4][HDIM];
    int t = threadIdx.x, lane = t & 63, sub = t >> 6;
    float wr[64];
    if (fw) {
        const float* Wb = (const float*)W3;
#pragma unroll
        for (int k = 0; k < 64; k++) wr[k] = Wb[k * HDIM + lane];
    } else {
        const __hip_bfloat16* Wb = (const __hip_bfloat16*)W3;
#pragma unroll
        for (int k = 0; k < 64; k++) wr[k] = __bfloat162float(Wb[k * HDIM + lane]);
    }
    float sc = scale[lane], sh = shift[lane];
    for (int v = blockIdx.x * 4 + sub; v < N_NODES; v += gridDim.x * 4) {
        float hv = bufB[(size_t)v * HDIM + lane];
        float r = fmaxf(hv * sc + sh, 0.f) * dis[v];
        rows[sub][lane] = r;
        float acc = 0.f;
#pragma unroll
        for (int k4 = 0; k4 < 16; k4++) {
            float4 rr = *(const float4*)&rows[sub][k4 * 4];
            acc += rr.x * wr[k4 * 4 + 0] + rr.y * wr[k4 * 4 + 1]
                 + rr.z * wr[k4 * 4 + 2] + rr.w * wr[k4 * 4 + 3];
        }
        yt[(size_t)v * HDIM + lane] = __float2bfloat16(acc);
    }
}

// ---- 32-channel-half gather, wave-per-node, 16 rows/round (4 lanes x 16 B / row) ----
// row-half = 64 B = exactly 1 cache line; per-half working set 6.4 MB (sequential
// dispatch per half keeps L2 working set small). Fused BN stats (16 extra VGPRs).

__global__ void __launch_bounds__(256) s29_gather32h(const __hip_bfloat16* __restrict__ yt,
                                                     const void* bias, int add_bias, int half,
                                                     const float* __restrict__ dis,
                                                     const int* __restrict__ cursor,
                                                     const int* __restrict__ csr,
                                                     float* __restrict__ bufB,
                                                     float* __restrict__ sums,
                                                     float* __restrict__ sumsq, int do_stats,
                                                     const int* __restrict__ fl) {
    int f1d = fl[2];
    int t = threadIdx.x, lane = t & 63, sub = t >> 6;
    int r = lane >> 2, s = lane & 3;
    int ch0 = half * 32;
    __shared__ float bsh[32];
    __shared__ float ws[4][4][16];
    if (t < 32) bsh[t] = add_bias ? ldf(bias, ch0 + t, f1d) : 0.f;
    __syncthreads();
    float4 sa = make_float4(0.f, 0.f, 0.f, 0.f), sb = make_float4(0.f, 0.f, 0.f, 0.f);
    float4 qa = make_float4(0.f, 0.f, 0.f, 0.f), qb = make_float4(0.f, 0.f, 0.f, 0.f);
    const __hip_bfloat16* ybase = yt + ch0;
    int stride = gridDim.x * 4;
    for (int v = blockIdx.x * 4 + sub; v < N_NODES; v += stride) {
        int end = cursor[v];
        int start = (v == 0) ? 0 : cursor[v - 1];
        int vlen = end - start + 1;                  // [self] ++ neighbors
        float4 b0 = make_float4(0.f, 0.f, 0.f, 0.f);
        float4 b1 = make_float4(0.f, 0.f, 0.f, 0.f);
        for (int k = 0; k < vlen; k += 16) {
            int i = k + r;
            if (i < vlen) {
                int rr = (i == 0) ? v : csr[start + i - 1];
                uint4 u = *(const uint4*)(ybase + (size_t)rr * HDIM + s * 8);
                upadd4(u, b0, b1);
            }
        }
        // combine 16 rows: lanes differing in bits 2..5
#pragma unroll
        for (int m = 4; m < 64; m <<= 1) {
            b0.x += __shfl_xor(b0.x, m); b0.y += __shfl_xor(b0.y, m);
            b0.z += __shfl_xor(b0.z, m); b0.w += __shfl_xor(b0.w, m);
            b1.x += __shfl_xor(b1.x, m); b1.y += __shfl_xor(b1.y, m);
            b1.z += __shfl_xor(b1.z, m); b1.w += __shfl_xor(b1.w, m);
        }
        if (r == 0) {                                // lanes 0..3 hold ch s*8..s*8+7
            float dv = dis[v];
            int ch = s * 8;
            float4 w0, w1;
            w0.x = b0.x * dv + bsh[ch + 0]; w0.y = b0.y * dv + bsh[ch + 1];
            w0.z = b0.z * dv + bsh[ch + 2]; w0.w = b0.w * dv + bsh[ch + 3];
            w1.x = b1.x * dv + bsh[ch + 4]; w1.y = b1.y * dv + bsh[ch + 5];
            w1.z = b1.z * dv + bsh[ch + 6]; w1.w = b1.w * dv + bsh[ch + 7];
            float4* dst = (float4*)&bufB[(size_t)v * HDIM + ch0 + ch];
            dst[0] = w0; dst[1] = w1;
            if (do_stats) {
                sa.x += w0.x; sa.y += w0.y; sa.z += w0.z; sa.w += w0.w;
                sb.x += w1.x; sb.y += w1.y; sb.z += w1.z; sb.w += w1.w;
                qa.x += w0.x * w0.x; qa.y += w0.y * w0.y;
                qa.z += w0.z * w0.z; qa.w += w0.w * w0.w;
                qb.x += w1.x * w1.x; qb.y += w1.y * w1.y;
                qb.z += w1.z * w1.z; qb.w += w1.w * w1.w;
            }
        }
    }
    if (do_stats) {
        if (r == 0) {
            float* wp = &ws[sub][s][0];
            wp[0] = sa.x; wp[1] = sa.y; wp[2] = sa.z; wp[3] = sa.w;
            wp[4] = sb.x; wp[5] = sb.y; wp[6] = sb.z; wp[7] = sb.w;
            wp[8] = qa.x; wp[9] = qa.y; wp[10] = qa.z; wp[11] = qa.w;
            wp[12] = qb.x; wp[13] = qb.y; wp[14] = qb.z; wp[15] = qb.w;
        }
        __syncthreads();
        if (t < 64) {
            int ss = t >> 4, j = t & 15;
            float tot = ws[0][ss][j] + ws[1][ss][j] + ws[2][ss][j] + ws[3][ss][j];
            int ch = ch0 + ss * 8 + (j & 7);
            if (j < 8) atomicAdd(&sums[ch], tot);
            else       atomicAdd(&sumsq[ch], tot);
        }
    }
}

__global__ void s22_bn_final(float* sums, float* sumsq, const void* gamma, const void* beta,
                             float* scale, float* shift, const int* __restrict__ fl) {
    int f1d = fl[2];
    int j = threadIdx.x;
    float mean = sums[j] / (float)N_NODES;
    float var  = sumsq[j] / (float)N_NODES - mean * mean;
    float sc = ldf(gamma, j, f1d) * rsqrtf(var + EPSF);
    scale[j] = sc;
    shift[j] = ldf(beta, j, f1d) - mean * sc;
    sums[j] = 0.f; sumsq[j] = 0.f;
}

// merged pool + head, 256 threads: 4-way row-parallel pooling then head
__global__ void __launch_bounds__(256) s22_pool_head(const float* __restrict__ bufB,
                                                     const int* __restrict__ batch,
                                                     const void* b3,
                                                     const void* gfeat, const void* Wg, const void* bg,
                                                     const void* Wp1, const void* bp1,
                                                     const void* Wp2, const void* bp2,
                                                     float* __restrict__ out,
                                                     const int* __restrict__ fl) {
    int f1d = fl[2], fw = fl[3], wide = fl[1];
    int g = blockIdx.x, t = threadIdx.x;
    int ch = t & 63, rp = t >> 6;
    __shared__ int se[2];
    __shared__ float part[4][HDIM];
    __shared__ float comb[HDIM + HDIM / 2];
    __shared__ float hid[HDIM];
    if (t < 2) {
        int target = g + t;
        int lo = 0, hi = N_NODES;
        while (lo < hi) {
            int mid = (lo + hi) >> 1;
            if (ld_batch(batch, mid, wide) < target) lo = mid + 1; else hi = mid;
        }
        se[t] = lo;
    }
    __syncthreads();
    int s = se[0], e = se[1];
    float sum = 0.f;
    for (int v = s + rp; v < e; v += 4) sum += bufB[(size_t)v * HDIM + ch];
    part[rp][ch] = sum;
    __syncthreads();
    if (t < HDIM) {
        float tot = part[0][ch] + part[1][ch] + part[2][ch] + part[3][ch];
        float cnt = (float)(e - s);
        comb[ch] = (cnt > 0.f) ? (tot / cnt + ldf(b3, ch, f1d)) : 0.f;
        if (ch < HDIM / 2) {
            float a = ldf(bg, ch, f1d);
#pragma unroll
            for (int k = 0; k < GFEAT; k++)
                a += ldf(gfeat, g * GFEAT + k, fw) * ldf(Wg, k * (HDIM / 2) + ch, fw);
            comb[HDIM + ch] = fmaxf(a, 0.f);
        }
    }
    __syncthreads();
    if (t < HDIM) {
        float a = ldf(bp1, ch, f1d);
        for (int k = 0; k < HDIM + HDIM / 2; k++) a += comb[k] * ldf(Wp1, k * HDIM + ch, fw);
        hid[ch] = fmaxf(a, 0.f);
    }
    __syncthreads();
    if (t < T_OUT) {
        float o = ldf(bp2, t, f1d);
#pragma unroll
        for (int k = 0; k < HDIM; k++) o += hid[k] * ldf(Wp2, k * T_OUT + t, fw);
        out[g * T_OUT + t] = o;
    }
}

extern "C" __attribute__((visibility("default")))
void kernel_launch(void* const* d_in, const int* in_sizes, int n_in,
                   void* d_out, int out_size, void* d_ws, size_t ws_size,
                   hipStream_t stream) {
    static const int exp_sizes[20] = {700000, 10000, 448, 64, 4096, 64, 4096, 64,
                                      64, 64, 64, 64, 320, 32, 6144, 64, 320, 5,
                                      2400000, 100000};
    bool ok = (n_in == 20) && (out_size == N_GRAPH * T_OUT);
    if (ok) for (int i = 0; i < 20; i++) ok = ok && (in_sizes[i] == exp_sizes[i]);
    if (!ok) {
        s22_fill<<<(out_size + 255) / 256, 256, 0, stream>>>((float*)d_out, out_size, 900.0f);
        return;
    }

    const void* x      = d_in[0];
    const void* gfeat  = d_in[1];
    const void* W1     = d_in[2];
    const void* b1     = d_in[3];
    const void* W2     = d_in[4];
    const void* b2     = d_in[5];
    const void* W3     = d_in[6];
    const void* b3     = d_in[7];
    const void* gamma1 = d_in[8];
    const void* beta1  = d_in[9];
    const void* gamma2 = d_in[10];
    const void* beta2  = d_in[11];
    const void* Wg     = d_in[12];
    const void* bg     = d_in[13];
    const void* Wp1    = d_in[14];
    const void* bp1    = d_in[15];
    const void* Wp2    = d_in[16];
    const void* bp2    = d_in[17];
    const int* edge  = (const int*)d_in[18];
    const int* batch = (const int*)d_in[19];

    // workspace layout (4-byte words)
    int*   flags   = (int*)d_ws;                        // 32
    int*   degi    = flags + 32;                        // N (bucket arrays live here)
    float* dis     = (float*)(degi + N_NODES);          // N
    float* cnts    = dis + N_NODES;                     // G (padding)
    float* sums    = cnts + N_GRAPH;                    // H
    float* sumsq   = sums + HDIM;                       // H
    float* scale   = sumsq + HDIM;                      // H
    float* shift   = scale + HDIM;                      // H
    float* pooled  = shift + HDIM;                      // G*H (mom lives here)
    int*   cursor  = (int*)(pooled + N_GRAPH * HDIM);   // N
    int*   bsum    = cursor + N_NODES;                  // 512 (unused)
    int*   csr_src = bsum + 512;                        // E
    __hip_bfloat16* xt = (__hip_bfloat16*)(csr_src + N_EDGES);  // N*8 bf16
    float* aggx    = (float*)(xt + (size_t)N_NODES * 8);        // N*8 fp32
    __hip_bfloat16* yt = (__hip_bfloat16*)(aggx + (size_t)N_NODES * 8);  // [N][64] bf16
    float* bufB    = (float*)(yt + (size_t)N_NODES * HDIM);     // N*H fp32

    // bucket-build scratch (aliases)
    int* bin_total  = degi;            // NBUK*16 (line-padded)
    int* bin_cursor = degi + 8192;     // NBUK*16 (line-padded)
    int* bbase      = degi + 16384;    // NBUK
    int* packed     = (int*)bufB;      // E ints (bufB first written in gather32h L2)
    float* mom      = pooled;          // 35 floats

    const size_t need = (size_t)(32 + 3 * N_NODES + N_GRAPH + 4 * HDIM + N_GRAPH * HDIM
                                 + 512 + N_EDGES + 4 * N_NODES + 8 * N_NODES
                                 + 32 * N_NODES + 64 * (size_t)N_NODES) * 4;
    if (ws_size < need) {
        s22_fill<<<(out_size + 255) / 256, 256, 0, stream>>>((float*)d_out, out_size, 500.0f);
        return;
    }

    s22_probe<<<1, 256, 0, stream>>>(edge, batch, (const unsigned*)gamma1,
                                     (const unsigned short*)x, (const unsigned short*)W1,
                                     (const unsigned short*)W2, flags);

    s22_zero<<<(NBUK * 16 + 255) / 256, 256, 0, stream>>>(bin_total, NBUK * 16);
    s22_zero<<<2, 256, 0, stream>>>((int*)sums, 4 * HDIM + 64);   // sums,sumsq,scale,shift,mom

    // bucketed CSR build (x̃ prep fused into fill)
    s23_count<<<NBLK_E, 256, 0, stream>>>(edge, bin_total, flags);
    s23_scanbk<<<1, 512, 0, stream>>>(bin_total, bbase, bin_cursor);
    s23_scatter<<<NBLK_E, 256, 0, stream>>>(edge, bin_cursor, packed, flags);
    s23_fill<<<NBUK, 256, 0, stream>>>(packed, bbase, bin_total, csr_src, cursor, dis,
                                       x, xt, flags);

    // layer 1: gather (+ fused BN1 moments)
    s28_gather_x_mom<<<512, 256, 0, stream>>>(xt, dis, cursor, csr_src, aggx, mom);
    s24_bn1<<<1, 64, 0, stream>>>(mom, W1, b1, gamma1, beta1, scale, shift, flags);

    // layer 2: prep + half-table gathers (sequential halves; stats fused)
    s24_prep2<<<1024, 256, 0, stream>>>(aggx, W1, W2, scale, shift, dis, yt, flags);
    s29_gather32h<<<2048, 256, 0, stream>>>(yt, b2, 1, 0, dis, cursor, csr_src, bufB,
                                            sums, sumsq, 1, flags);
    s29_gather32h<<<2048, 256, 0, stream>>>(yt, b2, 1, 1, dis, cursor, csr_src, bufB,
                                            sums, sumsq, 1, flags);
    s22_bn_final<<<1, 64, 0, stream>>>(sums, sumsq, gamma2, beta2, scale, shift, flags);

    // layer 3
    s24_prep3<<<1024, 256, 0, stream>>>(bufB, W3, scale, shift, dis, yt, flags);
    s29_gather32h<<<2048, 256, 0, stream>>>(yt, b3, 0, 0, dis, cursor, csr_src, bufB,
                                            sums, sumsq, 0, flags);
    s29_gather32h<<<2048, 256, 0, stream>>>(yt, b3, 0, 1, dis, cursor, csr_src, bufB,
                                            sums, sumsq, 0, flags);

    // pool + head
    s22_pool_head<<<N_GRAPH, 256, 0, stream>>>(bufB, batch, b3, gfeat, Wg, bg,
                                               Wp1, bp1, Wp2, bp2, (float*)d_out, flags);
}

// Round 10
// 419.056 us; speedup vs baseline: 1.2067x; 1.2067x over previous
//
#include <hip/hip_runtime.h>
#include <hip/hip_bf16.h>

#define N_NODES 100000
#define N_EDGES 1200000
#define N_GRAPH 1000
#define F_INN   7
#define HDIM    64
#define GFEAT   10
#define T_OUT   5
#define EPSF    1e-5f
#define NG64    ((N_NODES + 63) / 64)       // 1563
#define NBUK    ((N_NODES + 255) / 256)     // 391 buckets of 256 nodes
#define EPB     4096                        // edges per block (count/scatter)
#define NBLK_E  ((N_EDGES + EPB - 1) / EPB) // 293
#define NBLK_G64 ((N_NODES + 3) / 4)        // 25000 (wave-per-node gather)

// flags: [0]=edge wide(int64) [1]=batch wide [2]=1D fp32 [3]=world fp32

__device__ __forceinline__ float ldf(const void* p, int i, int isf32) {
    return isf32 ? ((const float*)p)[i]
                 : __bfloat162float(((const __hip_bfloat16*)p)[i]);
}
__device__ __forceinline__ float u_lo(unsigned u) { return __uint_as_float(u << 16); }
__device__ __forceinline__ float u_hi(unsigned u) { return __uint_as_float(u & 0xFFFF0000u); }
// spill-proof: named float4 accumulators only
__device__ __forceinline__ void upadd4(uint4 u, float4& p, float4& q) {
    p.x += u_lo(u.x); p.y += u_hi(u.x);
    p.z += u_lo(u.y); p.w += u_hi(u.y);
    q.x += u_lo(u.z); q.y += u_hi(u.z);
    q.z += u_lo(u.w); q.w += u_hi(u.w);
}
__device__ __forceinline__ int ld_src(const int* edge, int e, int wide) {
    return wide ? edge[2 * e] : edge[e];
}
__device__ __forceinline__ int ld_dst(const int* edge, int e, int wide) {
    return wide ? edge[2 * (N_EDGES + e)] : edge[N_EDGES + e];
}
__device__ __forceinline__ int ld_batch(const int* batch, int v, int wide) {
    return wide ? batch[2 * v] : batch[v];
}

__global__ void SimpleGCN_6640019440134_kernel() {}

__global__ void s22_fill(float* out, int n, float val) {
    int i = blockIdx.x * blockDim.x + threadIdx.x;
    if (i < n) out[i] = val;
}

// ---- merged init: zero bucket counters + zero stats region + input probe ----

__global__ void __launch_bounds__(256) s30_init(int* bin_total, int* sums_region,
                                                const int* edge, const int* batch,
                                                const unsigned* g1,
                                                const unsigned short* x,
                                                const unsigned short* W1,
                                                const unsigned short* W2,
                                                int* flags) {
    int b = blockIdx.x, t = threadIdx.x;
    if (b < 25) {
        int i = b * 256 + t;
        if (i < NBUK * 16) bin_total[i] = 0;
        return;
    }
    if (b == 25) {
        if (t < 4 * HDIM + 64) sums_region[t] = 0;   // sums,sumsq,scale,shift,mom
        return;
    }
    // probe block
    __shared__ int sh[8];
    if (t < 8) sh[t] = 0;
    __syncthreads();
    { int pos = 1 + 2 * 4687 * t; if (edge[pos] != 0) atomicOr(&sh[0], 1); }
    { int pos = (N_NODES - 511) + 2 * t; if (batch[pos] != 0) atomicOr(&sh[1], 1); }
    if (t < 16 && g1[t] != 0x3F800000u) atomicOr(&sh[2], 1);
    {
        int e = (x[t] >> 7) & 0xFF;  if (e >= 100 && e <= 140) atomicAdd(&sh[3], 1);
        e = (W1[t] >> 7) & 0xFF;     if (e >= 100 && e <= 140) atomicAdd(&sh[4], 1);
        e = (W2[t] >> 7) & 0xFF;     if (e >= 100 && e <= 140) atomicAdd(&sh[5], 1);
    }
    __syncthreads();
    if (t == 0) {
        flags[0] = (sh[0] == 0);
        flags[1] = (sh[1] == 0);
        flags[2] = (sh[2] == 0);
        int fx = (sh[3] < 192), fw1 = (sh[4] < 192), fw2 = (sh[5] < 192);
        flags[3] = (fx + fw1 + fw2 >= 2);
    }
}

// ---- bucketed CSR build: count -> scan buckets -> scatter packed -> fine fill ----
// bucket b covers dst nodes [b*256, b*256+256); packed word = src | (dst&255)<<17

__global__ void __launch_bounds__(256) s23_count(const int* __restrict__ edge,
                                                 int* __restrict__ bin_total,
                                                 const int* __restrict__ fl) {
    __shared__ int hist[NBUK];
    int wide = fl[0];
    int t = threadIdx.x;
    for (int i = t; i < NBUK; i += 256) hist[i] = 0;
    __syncthreads();
    int e0 = blockIdx.x * EPB;
    int e1 = min(e0 + EPB, N_EDGES);
    for (int e = e0 + t; e < e1; e += 256) {
        unsigned d = (unsigned)ld_dst(edge, e, wide);
        unsigned s = (unsigned)ld_src(edge, e, wide);
        if (s < N_NODES && d < N_NODES) atomicAdd(&hist[d >> 8], 1);
    }
    __syncthreads();
    for (int i = t; i < NBUK; i += 256) {
        int c = hist[i];
        if (c) atomicAdd(&bin_total[i * 16], c);   // line-padded counters
    }
}

__global__ void __launch_bounds__(512) s23_scanbk(const int* __restrict__ bin_total,
                                                  int* __restrict__ bbase,
                                                  int* __restrict__ bin_cursor) {
    __shared__ int tmp[512];
    int t = threadIdx.x;
    int v = (t < NBUK) ? bin_total[t * 16] : 0;
    tmp[t] = v;
    __syncthreads();
    for (int o = 1; o < 512; o <<= 1) {
        int a = (t >= o) ? tmp[t - o] : 0;
        __syncthreads();
        tmp[t] += a;
        __syncthreads();
    }
    if (t < NBUK) {
        int b = tmp[t] - v;       // exclusive prefix = bucket base
        bbase[t] = b;
        bin_cursor[t * 16] = b;
    }
}

__global__ void __launch_bounds__(256) s23_scatter(const int* __restrict__ edge,
                                                   int* __restrict__ bin_cursor,
                                                   int* __restrict__ packed,
                                                   const int* __restrict__ fl) {
    __shared__ int hist[NBUK];
    __shared__ int bloc[NBUK];
    int wide = fl[0];
    int t = threadIdx.x;
    for (int i = t; i < NBUK; i += 256) hist[i] = 0;
    __syncthreads();
    int e0 = blockIdx.x * EPB;
    int e1 = min(e0 + EPB, N_EDGES);
    for (int e = e0 + t; e < e1; e += 256) {
        unsigned d = (unsigned)ld_dst(edge, e, wide);
        unsigned s = (unsigned)ld_src(edge, e, wide);
        if (s < N_NODES && d < N_NODES) atomicAdd(&hist[d >> 8], 1);
    }
    __syncthreads();
    for (int i = t; i < NBUK; i += 256) {
        int c = hist[i];
        bloc[i] = c ? atomicAdd(&bin_cursor[i * 16], c) : 0;  // one alloc per (block,bucket)
        hist[i] = 0;                                          // reuse as rank counter
    }
    __syncthreads();
    for (int e = e0 + t; e < e1; e += 256) {
        unsigned d = (unsigned)ld_dst(edge, e, wide);
        unsigned s = (unsigned)ld_src(edge, e, wide);
        if (s < N_NODES && d < N_NODES) {
            int b = (int)(d >> 8);
            int r = atomicAdd(&hist[b], 1);
            packed[bloc[b] + r] = (int)s | ((int)(d & 255u) << 17);
        }
    }
}

// rank-scatter + fused x̃ prep (no sort — wave-per-node gathers can't exploit it)
__global__ void __launch_bounds__(256) s23_fill(const int* __restrict__ packed,
                                                const int* __restrict__ bbase,
                                                const int* __restrict__ bin_total,
                                                int* __restrict__ csr_src,
                                                int* __restrict__ cursor,
                                                float* __restrict__ dis,
                                                const void* x,
                                                __hip_bfloat16* __restrict__ xt,
                                                const int* __restrict__ fl) {
    __shared__ int ldeg[256];
    __shared__ int lrank[256];
    __shared__ int lstart[256];
    __shared__ int tmp[256];
    int b = blockIdx.x, t = threadIdx.x;
    int pb = bbase[b];
    int cnt = bin_total[b * 16];
    int fw = fl[3];
    ldeg[t] = 0; lrank[t] = 0;
    __syncthreads();
    for (int i = t; i < cnt; i += 256) {
        int vl = packed[pb + i] >> 17;
        atomicAdd(&ldeg[vl], 1);
    }
    __syncthreads();
    int dv = ldeg[t];
    tmp[t] = dv;
    __syncthreads();
    for (int o = 1; o < 256; o <<= 1) {
        int a = (t >= o) ? tmp[t - o] : 0;
        __syncthreads();
        tmp[t] += a;
        __syncthreads();
    }
    lstart[t] = tmp[t] - dv;           // bucket-local exclusive prefix
    int v = b * 256 + t;
    if (v < N_NODES) {
        cursor[v] = pb + tmp[t];       // global inclusive end offset
        float dvf = rsqrtf((float)dv + 1.0f);
        dis[v] = dvf;
#pragma unroll
        for (int c = 0; c < 8; c++) {
            float val = (c < F_INN) ? ldf(x, v * F_INN + c, fw) * dvf : 0.f;
            xt[(size_t)v * 8 + c] = __float2bfloat16(val);
        }
    }
    __syncthreads();
    for (int i = t; i < cnt; i += 256) {
        int p = packed[pb + i];
        int vl = p >> 17;
        int r = atomicAdd(&lrank[vl], 1);
        csr_src[pb + lstart[vl] + r] = p & 0x1FFFF;
    }
}

// ---- layer-1 gather (16 B rows, 1.6 MB table = L2-hot) + fused BN1 moments ----

__global__ void __launch_bounds__(256) s28_gather_x_mom(const __hip_bfloat16* __restrict__ xt,
                                                        const float* __restrict__ dis,
                                                        const int* __restrict__ cursor,
                                                        const int* __restrict__ csr,
                                                        float* __restrict__ aggx,
                                                        float* __restrict__ mom) {
    const uint4* rows = (const uint4*)xt;
    int t = threadIdx.x, lane = t & 63, sub = t >> 6;
    float m[7] = {0, 0, 0, 0, 0, 0, 0};
    float M[28];
#pragma unroll
    for (int i = 0; i < 28; i++) M[i] = 0.f;
    for (int grp = blockIdx.x * 4 + sub; grp < NG64; grp += gridDim.x * 4) {
        int v = grp * 64 + lane;
        if (v >= N_NODES) continue;
        int end = cursor[v];
        int start = (v == 0) ? 0 : cursor[v - 1];
        float4 b0 = make_float4(0.f, 0.f, 0.f, 0.f);
        float4 b1 = make_float4(0.f, 0.f, 0.f, 0.f);
        { uint4 u = rows[v]; upadd4(u, b0, b1); }
        int j = start;
        for (; j + 3 < end; j += 4) {
            uint4 u0 = rows[csr[j]], u1 = rows[csr[j + 1]];
            uint4 u2 = rows[csr[j + 2]], u3 = rows[csr[j + 3]];
            upadd4(u0, b0, b1); upadd4(u1, b0, b1);
            upadd4(u2, b0, b1); upadd4(u3, b0, b1);
        }
        for (; j < end; j++) { uint4 u = rows[csr[j]]; upadd4(u, b0, b1); }
        float dv = dis[v];
        float av[7] = {b0.x * dv, b0.y * dv, b0.z * dv, b0.w * dv,
                       b1.x * dv, b1.y * dv, b1.z * dv};
        float4* dst = (float4*)&aggx[(size_t)v * 8];
        dst[0] = make_float4(av[0], av[1], av[2], av[3]);
        dst[1] = make_float4(av[4], av[5], av[6], b1.w * dv);
#pragma unroll
        for (int c = 0; c < 7; c++) m[c] += av[c];
        int idx = 0;
#pragma unroll
        for (int c = 0; c < 7; c++)
#pragma unroll
            for (int d = c; d < 7; d++) { M[idx] += av[c] * av[d]; idx++; }
    }
#pragma unroll
    for (int c = 0; c < 7; c++)
        for (int mm = 1; mm < 64; mm <<= 1) m[c] += __shfl_xor(m[c], mm);
#pragma unroll
    for (int i = 0; i < 28; i++)
        for (int mm = 1; mm < 64; mm <<= 1) M[i] += __shfl_xor(M[i], mm);
    __shared__ float ws[4][35];
    if (lane == 0) {
#pragma unroll
        for (int c = 0; c < 7; c++) ws[sub][c] = m[c];
#pragma unroll
        for (int i = 0; i < 28; i++) ws[sub][7 + i] = M[i];
    }
    __syncthreads();
    if (t < 35) {
        float tot = ws[0][t] + ws[1][t] + ws[2][t] + ws[3][t];
        atomicAdd(&mom[t], tot);
    }
}

// ---- layer-2 prep with INLINE BN1 (scale/shift recomputed per block from mom) ----
// agg(8f) -> h=agg@W1 -> bn/relu/dis -> @W2 -> yt [N][64] bf16

__global__ void __launch_bounds__(256) s32_prep2(const float* __restrict__ aggx,
                                                 const void* W1, const void* W2,
                                                 const void* b1,
                                                 const void* gamma, const void* beta,
                                                 const float* __restrict__ mom,
                                                 const float* __restrict__ dis,
                                                 __hip_bfloat16* __restrict__ yt,
                                                 const int* __restrict__ fl) {
    int fw = fl[3], f1d = fl[2];
    __shared__ float rows[4][HDIM];
    int t = threadIdx.x, lane = t & 63, sub = t >> 6;
    float w1r[7], wr[64];
    if (fw) {
        const float* Wa = (const float*)W1;
        const float* Wb = (const float*)W2;
#pragma unroll
        for (int c = 0; c < 7; c++) w1r[c] = Wa[c * HDIM + lane];
#pragma unroll
        for (int k = 0; k < 64; k++) wr[k] = Wb[k * HDIM + lane];
    } else {
        const __hip_bfloat16* Wa = (const __hip_bfloat16*)W1;
        const __hip_bfloat16* Wb = (const __hip_bfloat16*)W2;
#pragma unroll
        for (int c = 0; c < 7; c++) w1r[c] = __bfloat162float(Wa[c * HDIM + lane]);
#pragma unroll
        for (int k = 0; k < 64; k++) wr[k] = __bfloat162float(Wb[k * HDIM + lane]);
    }
    // inline BN1 from moments (identical math to old s24_bn1)
    float sc, sh;
    {
        const float invN = 1.0f / (float)N_NODES;
        float b = ldf(b1, lane, f1d);
        float meanP = 0.f;
#pragma unroll
        for (int c = 0; c < 7; c++) meanP += mom[c] * w1r[c];
        meanP *= invN;
        float E2 = 0.f;
        int idx = 0;
#pragma unroll
        for (int c = 0; c < 7; c++)
#pragma unroll
            for (int d = c; d < 7; d++) {
                float f = (c == d) ? 1.f : 2.f;
                E2 += f * mom[7 + idx] * w1r[c] * w1r[d];
                idx++;
            }
        E2 *= invN;
        float mean = meanP + b;
        float var = E2 + 2.f * b * meanP + b * b - mean * mean;
        sc = ldf(gamma, lane, f1d) * rsqrtf(var + EPSF);
        sh = ldf(beta, lane, f1d) + (b - mean) * sc;
    }
    for (int v = blockIdx.x * 4 + sub; v < N_NODES; v += gridDim.x * 4) {
        const float4* p = (const float4*)&aggx[(size_t)v * 8];
        float4 a0 = p[0], a1 = p[1];
        float hb = a0.x * w1r[0] + a0.y * w1r[1] + a0.z * w1r[2] + a0.w * w1r[3]
                 + a1.x * w1r[4] + a1.y * w1r[5] + a1.z * w1r[6];
        float r = fmaxf(hb * sc + sh, 0.f) * dis[v];
        rows[sub][lane] = r;      // wave-private row; lockstep => no barrier
        float acc = 0.f;
#pragma unroll
        for (int k4 = 0; k4 < 16; k4++) {
            float4 rr = *(const float4*)&rows[sub][k4 * 4];
            acc += rr.x * wr[k4 * 4 + 0] + rr.y * wr[k4 * 4 + 1]
                 + rr.z * wr[k4 * 4 + 2] + rr.w * wr[k4 * 4 + 3];
        }
        yt[(size_t)v * HDIM + lane] = __float2bfloat16(acc);
    }
}

// ---- layer-3 prep with INLINE BN2-final (from sums/sumsq) ----

__global__ void __launch_bounds__(256) s33_prep3(const float* __restrict__ bufB,
                                                 const void* W3,
                                                 const float* __restrict__ sums,
                                                 const float* __restrict__ sumsq,
                                                 const void* gamma, const void* beta,
                                                 const float* __restrict__ dis,
                                                 __hip_bfloat16* __restrict__ yt,
                                                 const int* __restrict__ fl) {
    int fw = fl[3], f1d = fl[2];
    __shared__ float rows[4][HDIM];
    int t = threadIdx.x, lane = t & 63, sub = t >> 6;
    float wr[64];
    if (fw) {
        const float* Wb = (const float*)W3;
#pragma unroll
        for (int k = 0; k < 64; k++) wr[k] = Wb[k * HDIM + lane];
    } else {
        const __hip_bfloat16* Wb = (const __hip_bfloat16*)W3;
#pragma unroll
        for (int k = 0; k < 64; k++) wr[k] = __bfloat162float(Wb[k * HDIM + lane]);
    }
    float mean = sums[lane] / (float)N_NODES;
    float var  = sumsq[lane] / (float)N_NODES - mean * mean;
    float sc = ldf(gamma, lane, f1d) * rsqrtf(var + EPSF);
    float sh = ldf(beta, lane, f1d) - mean * sc;
    for (int v = blockIdx.x * 4 + sub; v < N_NODES; v += gridDim.x * 4) {
        float hv = bufB[(size_t)v * HDIM + lane];
        float r = fmaxf(hv * sc + sh, 0.f) * dis[v];
        rows[sub][lane] = r;
        float acc = 0.f;
#pragma unroll
        for (int k4 = 0; k4 < 16; k4++) {
            float4 rr = *(const float4*)&rows[sub][k4 * 4];
            acc += rr.x * wr[k4 * 4 + 0] + rr.y * wr[k4 * 4 + 1]
                 + rr.z * wr[k4 * 4 + 2] + rr.w * wr[k4 * 4 + 3];
        }
        yt[(size_t)v * HDIM + lane] = __float2bfloat16(acc);
    }
}

// ---- 64-channel gather, wave-per-node, oct-coalesced (r8-proven), layer 3 ----

__global__ void __launch_bounds__(256) s27_gather64(const __hip_bfloat16* __restrict__ yt,
                                                    const float* __restrict__ dis,
                                                    const int* __restrict__ cursor,
                                                    const int* __restrict__ csr,
                                                    float* __restrict__ bufB) {
    int t = threadIdx.x, lane = t & 63, sub = t >> 6;
    int o = lane >> 3, s = lane & 7;
    int v = blockIdx.x * 4 + sub;
    if (v >= N_NODES) return;
    int end = cursor[v];
    int start = (v == 0) ? 0 : cursor[v - 1];
    int vlen = end - start + 1;                  // [self] ++ neighbors
    float4 b0 = make_float4(0.f, 0.f, 0.f, 0.f);
    float4 b1 = make_float4(0.f, 0.f, 0.f, 0.f);
    for (int k = 0; k < vlen; k += 8) {
        int i = k + o;
        if (i < vlen) {
            int r = (i == 0) ? v : csr[start + i - 1];
            const uint4* p = (const uint4*)(yt + (size_t)r * HDIM + s * 8);
            uint4 u = *p;
            upadd4(u, b0, b1);
        }
    }
    for (int m = 8; m < 64; m <<= 1) {
        b0.x += __shfl_xor(b0.x, m); b0.y += __shfl_xor(b0.y, m);
        b0.z += __shfl_xor(b0.z, m); b0.w += __shfl_xor(b0.w, m);
        b1.x += __shfl_xor(b1.x, m); b1.y += __shfl_xor(b1.y, m);
        b1.z += __shfl_xor(b1.z, m); b1.w += __shfl_xor(b1.w, m);
    }
    if (o < 2) {
        float dv = dis[v];
        float4 bs = (o == 0) ? b0 : b1;
        float4 w = make_float4(bs.x * dv, bs.y * dv, bs.z * dv, bs.w * dv);
        *(float4*)&bufB[(size_t)v * HDIM + s * 8 + o * 4] = w;
    }
}

// ---- layer-2 variant: grid-stride + fused BN2 stats ----

__global__ void __launch_bounds__(256) s31_gather64s(const __hip_bfloat16* __restrict__ yt,
                                                     const void* bias,
                                                     const float* __restrict__ dis,
                                                     const int* __restrict__ cursor,
                                                     const int* __restrict__ csr,
                                                     float* __restrict__ bufB,
                                                     float* __restrict__ sums,
                                                     float* __restrict__ sumsq,
                                                     const int* __restrict__ fl) {
    int f1d = fl[2];
    int t = threadIdx.x, lane = t & 63, sub = t >> 6;
    int o = lane >> 3, s = lane & 7;
    float4 bb = make_float4(0.f, 0.f, 0.f, 0.f);
    if (o < 2) {
        int ch = s * 8 + o * 4;
        bb.x = ldf(bias, ch + 0, f1d); bb.y = ldf(bias, ch + 1, f1d);
        bb.z = ldf(bias, ch + 2, f1d); bb.w = ldf(bias, ch + 3, f1d);
    }
    float4 ssum = make_float4(0.f, 0.f, 0.f, 0.f);
    float4 ssq  = make_float4(0.f, 0.f, 0.f, 0.f);
    int stride = gridDim.x * 4;
    for (int v = blockIdx.x * 4 + sub; v < N_NODES; v += stride) {
        int end = cursor[v];
        int start = (v == 0) ? 0 : cursor[v - 1];
        int vlen = end - start + 1;
        float4 b0 = make_float4(0.f, 0.f, 0.f, 0.f);
        float4 b1 = make_float4(0.f, 0.f, 0.f, 0.f);
        for (int k = 0; k < vlen; k += 8) {
            int i = k + o;
            if (i < vlen) {
                int r = (i == 0) ? v : csr[start + i - 1];
                const uint4* p = (const uint4*)(yt + (size_t)r * HDIM + s * 8);
                uint4 u = *p;
                upadd4(u, b0, b1);
            }
        }
        for (int m = 8; m < 64; m <<= 1) {
            b0.x += __shfl_xor(b0.x, m); b0.y += __shfl_xor(b0.y, m);
            b0.z += __shfl_xor(b0.z, m); b0.w += __shfl_xor(b0.w, m);
            b1.x += __shfl_xor(b1.x, m); b1.y += __shfl_xor(b1.y, m);
            b1.z += __shfl_xor(b1.z, m); b1.w += __shfl_xor(b1.w, m);
        }
        if (o < 2) {
            float dv = dis[v];
            float4 bs = (o == 0) ? b0 : b1;
            float4 w = make_float4(bs.x * dv + bb.x, bs.y * dv + bb.y,
                                   bs.z * dv + bb.z, bs.w * dv + bb.w);
            *(float4*)&bufB[(size_t)v * HDIM + s * 8 + o * 4] = w;
            ssum.x += w.x; ssum.y += w.y; ssum.z += w.z; ssum.w += w.w;
            ssq.x += w.x * w.x; ssq.y += w.y * w.y;
            ssq.z += w.z * w.z; ssq.w += w.w * w.w;
        }
    }
    __shared__ float ws[4][16][8];
    if (o < 2) {
        float* wp = &ws[sub][s * 2 + o][0];
        wp[0] = ssum.x; wp[1] = ssum.y; wp[2] = ssum.z; wp[3] = ssum.w;
        wp[4] = ssq.x;  wp[5] = ssq.y;  wp[6] = ssq.z;  wp[7] = ssq.w;
    }
    __syncthreads();
    if (t < 128) {
        int li = t >> 3, j = t & 7;
        float tot = ws[0][li][j] + ws[1][li][j] + ws[2][li][j] + ws[3][li][j];
        int ch = (li >> 1) * 8 + (li & 1) * 4 + (j & 3);
        if (j < 4) atomicAdd(&sums[ch], tot);
        else       atomicAdd(&sumsq[ch], tot);
    }
}

// merged pool + head, 256 threads: 4-way row-parallel pooling then head
__global__ void __launch_bounds__(256) s22_pool_head(const float* __restrict__ bufB,
                                                     const int* __restrict__ batch,
                                                     const void* b3,
                                                     const void* gfeat, const void* Wg, const void* bg,
                                                     const void* Wp1, const void* bp1,
                                                     const void* Wp2, const void* bp2,
                                                     float* __restrict__ out,
                                                     const int* __restrict__ fl) {
    int f1d = fl[2], fw = fl[3], wide = fl[1];
    int g = blockIdx.x, t = threadIdx.x;
    int ch = t & 63, rp = t >> 6;
    __shared__ int se[2];
    __shared__ float part[4][HDIM];
    __shared__ float comb[HDIM + HDIM / 2];
    __shared__ float hid[HDIM];
    if (t < 2) {
        int target = g + t;
        int lo = 0, hi = N_NODES;
        while (lo < hi) {
            int mid = (lo + hi) >> 1;
            if (ld_batch(batch, mid, wide) < target) lo = mid + 1; else hi = mid;
        }
        se[t] = lo;
    }
    __syncthreads();
    int s = se[0], e = se[1];
    float sum = 0.f;
    for (int v = s + rp; v < e; v += 4) sum += bufB[(size_t)v * HDIM + ch];
    part[rp][ch] = sum;
    __syncthreads();
    if (t < HDIM) {
        float tot = part[0][ch] + part[1][ch] + part[2][ch] + part[3][ch];
        float cnt = (float)(e - s);
        comb[ch] = (cnt > 0.f) ? (tot / cnt + ldf(b3, ch, f1d)) : 0.f;
        if (ch < HDIM / 2) {
            float a = ldf(bg, ch, f1d);
#pragma unroll
            for (int k = 0; k < GFEAT; k++)
                a += ldf(gfeat, g * GFEAT + k, fw) * ldf(Wg, k * (HDIM / 2) + ch, fw);
            comb[HDIM + ch] = fmaxf(a, 0.f);
        }
    }
    __syncthreads();
    if (t < HDIM) {
        float a = ldf(bp1, ch, f1d);
        for (int k = 0; k < HDIM + HDIM / 2; k++) a += comb[k] * ldf(Wp1, k * HDIM + ch, fw);
        hid[ch] = fmaxf(a, 0.f);
    }
    __syncthreads();
    if (t < T_OUT) {
        float o = ldf(bp2, t, f1d);
#pragma unroll
        for (int k = 0; k < HDIM; k++) o += hid[k] * ldf(Wp2, k * T_OUT + t, fw);
        out[g * T_OUT + t] = o;
    }
}

extern "C" __attribute__((visibility("default")))
void kernel_launch(void* const* d_in, const int* in_sizes, int n_in,
                   void* d_out, int out_size, void* d_ws, size_t ws_size,
                   hipStream_t stream) {
    static const int exp_sizes[20] = {700000, 10000, 448, 64, 4096, 64, 4096, 64,
                                      64, 64, 64, 64, 320, 32, 6144, 64, 320, 5,
                                      2400000, 100000};
    bool ok = (n_in == 20) && (out_size == N_GRAPH * T_OUT);
    if (ok) for (int i = 0; i < 20; i++) ok = ok && (in_sizes[i] == exp_sizes[i]);
    if (!ok) {
        s22_fill<<<(out_size + 255) / 256, 256, 0, stream>>>((float*)d_out, out_size, 900.0f);
        return;
    }

    const void* x      = d_in[0];
    const void* gfeat  = d_in[1];
    const void* W1     = d_in[2];
    const void* b1     = d_in[3];
    const void* W2     = d_in[4];
    const void* b2     = d_in[5];
    const void* W3     = d_in[6];
    const void* b3     = d_in[7];
    const void* gamma1 = d_in[8];
    const void* beta1  = d_in[9];
    const void* gamma2 = d_in[10];
    const void* beta2  = d_in[11];
    const void* Wg     = d_in[12];
    const void* bg     = d_in[13];
    const void* Wp1    = d_in[14];
    const void* bp1    = d_in[15];
    const void* Wp2    = d_in[16];
    const void* bp2    = d_in[17];
    const int* edge  = (const int*)d_in[18];
    const int* batch = (const int*)d_in[19];

    // workspace layout (4-byte words)
    int*   flags   = (int*)d_ws;                        // 32
    int*   degi    = flags + 32;                        // N (bucket arrays live here)
    float* dis     = (float*)(degi + N_NODES);          // N
    float* cnts    = dis + N_NODES;                     // G (padding)
    float* sums    = cnts + N_GRAPH;                    // H
    float* sumsq   = sums + HDIM;                       // H
    float* scale   = sumsq + HDIM;                      // H (unused)
    float* shift   = scale + HDIM;                      // H (unused)
    float* pooled  = shift + HDIM;                      // G*H (mom lives here)
    int*   cursor  = (int*)(pooled + N_GRAPH * HDIM);   // N
    int*   bsum    = cursor + N_NODES;                  // 512 (unused)
    int*   csr_src = bsum + 512;                        // E
    __hip_bfloat16* xt = (__hip_bfloat16*)(csr_src + N_EDGES);  // N*8 bf16
    float* aggx    = (float*)(xt + (size_t)N_NODES * 8);        // N*8 fp32
    __hip_bfloat16* yt = (__hip_bfloat16*)(aggx + (size_t)N_NODES * 8);  // [N][64] bf16
    float* bufB    = (float*)(yt + (size_t)N_NODES * HDIM);     // N*H fp32

    // bucket-build scratch (aliases)
    int* bin_total  = degi;            // NBUK*16 (line-padded)
    int* bin_cursor = degi + 8192;     // NBUK*16 (line-padded)
    int* bbase      = degi + 16384;    // NBUK
    int* packed     = (int*)bufB;      // E ints (bufB first written in gather64s L2)
    float* mom      = pooled;          // 35 floats

    const size_t need = (size_t)(32 + 3 * N_NODES + N_GRAPH + 4 * HDIM + N_GRAPH * HDIM
                                 + 512 + N_EDGES + 4 * N_NODES + 8 * N_NODES
                                 + 32 * N_NODES + 64 * (size_t)N_NODES) * 4;
    if (ws_size < need) {
        s22_fill<<<(out_size + 255) / 256, 256, 0, stream>>>((float*)d_out, out_size, 500.0f);
        return;
    }

    // 1: merged zero + probe
    s30_init<<<27, 256, 0, stream>>>(bin_total, (int*)sums, edge, batch,
                                     (const unsigned*)gamma1,
                                     (const unsigned short*)x, (const unsigned short*)W1,
                                     (const unsigned short*)W2, flags);
    // 2-5: bucketed CSR build (x̃ prep fused into fill)
    s23_count<<<NBLK_E, 256, 0, stream>>>(edge, bin_total, flags);
    s23_scanbk<<<1, 512, 0, stream>>>(bin_total, bbase, bin_cursor);
    s23_scatter<<<NBLK_E, 256, 0, stream>>>(edge, bin_cursor, packed, flags);
    s23_fill<<<NBUK, 256, 0, stream>>>(packed, bbase, bin_total, csr_src, cursor, dis,
                                       x, xt, flags);
    // 6: layer-1 gather + BN1 moments
    s28_gather_x_mom<<<512, 256, 0, stream>>>(xt, dis, cursor, csr_src, aggx, mom);
    // 7: prep2 (BN1 inline from moments)
    s32_prep2<<<1024, 256, 0, stream>>>(aggx, W1, W2, b1, gamma1, beta1, mom,
                                        dis, yt, flags);
    // 8: layer-2 gather (grid-stride, BN2 stats fused)
    s31_gather64s<<<2048, 256, 0, stream>>>(yt, b2, dis, cursor, csr_src, bufB,
                                            sums, sumsq, flags);
    // 9: prep3 (BN2 final inline from sums/sumsq)
    s33_prep3<<<1024, 256, 0, stream>>>(bufB, W3, sums, sumsq, gamma2, beta2,
                                        dis, yt, flags);
    // 10: layer-3 gather (r8-proven wave-per-node)
    s27_gather64<<<NBLK_G64, 256, 0, stream>>>(yt, dis, cursor, csr_src, bufB);
    // 11: pool + head
    s22_pool_head<<<N_GRAPH, 256, 0, stream>>>(bufB, batch, b3, gfeat, Wg, bg,
                                               Wp1, bp1, Wp2, bp2, (float*)d_out, flags);
}